// Round 17
// baseline (133.448 us; speedup 1.0000x reference)
//
#include <hip/hip_runtime.h>

// Int8 fake-quant linear (exact integer accumulation):
//   sx = max|x|/128; qx = clamp(rint(x/sx),-128,127)
//   sw = max|w|/127; qw = clamp(rint(w/sw),-127,127)
//   out = mul * (sx*sw*(qx @ qw^T) + bias)
//
// qx permuted in 128-row blocks:  v4i idx = ((blk*32+kt)*4 + c)*128 + r
// qw permuted in 256-row blocks:  v4i idx = ((blk*32+kt)*4 + c)*256 + r
// Staging is a linear contiguous copy (global_load_lds); fragment reads are
// 32-lane contiguous (0 bank conflicts, verified R3/R5/R7/R12/R15).

typedef int v4i  __attribute__((ext_vector_type(4)));
typedef int v16i __attribute__((ext_vector_type(16)));

#define MDIM 4096
#define NDIM 8192
#define KDIM 2048
#define NT   (KDIM / 64)   // 32 K-tiles of BK=64 int8

typedef __attribute__((address_space(1))) void* gas_ptr;   // global
typedef __attribute__((address_space(3))) void* las_ptr;   // LDS

#define XBLK 1024   // blocks for x; w gets 2048 (total 3072)

// ---------------- absmax: per-block partial maxima (plain stores) ----------------
__global__ __launch_bounds__(256) void absmax2(const float4* __restrict__ x,
                                               const float4* __restrict__ w,
                                               float* __restrict__ partial) {
    const int tid = threadIdx.x;
    const bool isx = blockIdx.x < XBLK;
    float m0 = 0.0f, m1 = 0.0f;
    if (isx) {
        const size_t base = (size_t)blockIdx.x * 256 + tid;       // stride 262144
#pragma unroll
        for (int j = 0; j < 8; j += 2) {
            float4 v0 = x[base + (size_t)j * 262144];
            float4 v1 = x[base + (size_t)(j + 1) * 262144];
            m0 = fmaxf(m0, fmaxf(fmaxf(fabsf(v0.x), fabsf(v0.y)),
                                 fmaxf(fabsf(v0.z), fabsf(v0.w))));
            m1 = fmaxf(m1, fmaxf(fmaxf(fabsf(v1.x), fabsf(v1.y)),
                                 fmaxf(fabsf(v1.z), fabsf(v1.w))));
        }
    } else {
        const size_t base = (size_t)(blockIdx.x - XBLK) * 256 + tid;  // stride 524288
#pragma unroll
        for (int j = 0; j < 8; j += 2) {
            float4 v0 = w[base + (size_t)j * 524288];
            float4 v1 = w[base + (size_t)(j + 1) * 524288];
            m0 = fmaxf(m0, fmaxf(fmaxf(fabsf(v0.x), fabsf(v0.y)),
                                 fmaxf(fabsf(v0.z), fabsf(v0.w))));
            m1 = fmaxf(m1, fmaxf(fmaxf(fabsf(v1.x), fabsf(v1.y)),
                                 fmaxf(fabsf(v1.z), fabsf(v1.w))));
        }
    }
    float m = fmaxf(m0, m1);
#pragma unroll
    for (int off = 32; off > 0; off >>= 1)
        m = fmaxf(m, __shfl_xor(m, off, 64));
    __shared__ float wm[4];
    if ((tid & 63) == 0) wm[tid >> 6] = m;
    __syncthreads();
    if (tid == 0)
        partial[blockIdx.x] = fmaxf(fmaxf(wm[0], wm[1]), fmaxf(wm[2], wm[3]));
}

// ---------------- quantize: reduce partials, then permuted int8 write ----------
// x -> 128-row blocks; w -> 256-row blocks.
__global__ __launch_bounds__(256) void quant2(const float4* __restrict__ x,
                                              v4i* __restrict__ qxp,
                                              const float4* __restrict__ w,
                                              v4i* __restrict__ qwp,
                                              const float* __restrict__ partial,
                                              unsigned* __restrict__ scales) {
    const int tid = threadIdx.x;
    float gx = 0.0f, gw = 0.0f;
#pragma unroll
    for (int j = 0; j < 4; ++j) gx = fmaxf(gx, partial[tid + j * 256]);
#pragma unroll
    for (int j = 0; j < 8; ++j) gw = fmaxf(gw, partial[XBLK + tid + j * 256]);
#pragma unroll
    for (int off = 32; off > 0; off >>= 1) {
        gx = fmaxf(gx, __shfl_xor(gx, off, 64));
        gw = fmaxf(gw, __shfl_xor(gw, off, 64));
    }
    __shared__ float smx[4], smw[4];
    if ((tid & 63) == 0) { smx[tid >> 6] = gx; smw[tid >> 6] = gw; }
    __syncthreads();
    const float fmx = fmaxf(fmaxf(smx[0], smx[1]), fmaxf(smx[2], smx[3]));
    const float fmw = fmaxf(fmaxf(smw[0], smw[1]), fmaxf(smw[2], smw[3]));
    if (blockIdx.x == 0 && tid == 0) {
        scales[0] = __float_as_uint(fmx);
        scales[1] = __float_as_uint(fmw);
    }
    const float sxs = fmx / 128.0f;   // IEEE, matches reference scale
    const float sws = fmw / 127.0f;

    const bool isx = blockIdx.x < XBLK;
    const float4* in = isx ? x : w;
    v4i* outp = isx ? qxp : qwp;
    const int total = isx ? (MDIM * KDIM / 16) : (NDIM * KDIM / 16);
    const int nb = isx ? XBLK : (3072 - XBLK);
    const int b  = isx ? blockIdx.x : (blockIdx.x - XBLK);
    const float s  = isx ? sxs : sws;
    const float lo = isx ? -128.0f : -127.0f;
    for (int idx = b * 256 + tid; idx < total; idx += nb * 256) {
        int c, r, kt, blk, row, oidx;
        if (isx) {   // 128-row blocks
            c   = idx & 3;
            r   = (idx >> 2) & 127;
            kt  = (idx >> 9) & 31;
            blk = idx >> 14;
            row = blk * 128 + r;
            oidx = ((blk * 32 + kt) * 4 + c) * 128 + r;
        } else {     // 256-row blocks
            c   = idx & 3;
            r   = (idx >> 2) & 255;
            kt  = (idx >> 10) & 31;
            blk = idx >> 15;
            row = blk * 256 + r;
            oidx = ((blk * 32 + kt) * 4 + c) * 256 + r;
        }
        const float4* src = in + (size_t)row * (KDIM / 4) + kt * 16 + c * 4;
        int q[4];
#pragma unroll
        for (int j = 0; j < 4; ++j) {
            float4 v = src[j];
            int b0 = (int)fminf(fmaxf(rintf(v.x / s), lo), 127.0f);
            int b1 = (int)fminf(fmaxf(rintf(v.y / s), lo), 127.0f);
            int b2 = (int)fminf(fmaxf(rintf(v.z / s), lo), 127.0f);
            int b3 = (int)fminf(fmaxf(rintf(v.w / s), lo), 127.0f);
            q[j] = (b0 & 255) | ((b1 & 255) << 8) | ((b2 & 255) << 16) | (b3 << 24);
        }
        v4i qq; qq[0] = q[0]; qq[1] = q[1]; qq[2] = q[2]; qq[3] = q[3];
        outp[oidx] = qq;
    }
}

// ------- int8 MFMA GEMM: 128x256 tile, ring-3, 2 blocks/CU, 1 barrier/tile ---
// 256 threads = 4 waves (1M x 4N); wave output 128x64 = 4x2 mfma_i32_32x32x32.
// LDS: A 8KB + B 16KB per buffer, ring-3 = 72 KiB -> TWO blocks/CU (m114
// cross-block overlap, R15-proven). Supertile: each XCD owns 16 bm x 8 bn.
// SINGLE barrier per tile (R16-proven): {stage kt+2 (6 loads, issued FIRST);
// 12 ds_read_b128(t); 16 MFMA; vmcnt(6|0); s_barrier}.
// R17 A/B vs R16: (1) NO setprio -- in the 2-block regime, boosting the
// MFMA-ing block starves the other block's read/stage issue (phase-locking);
// (2) stage issued before the ds_reads so the global loads are ~150cyc
// deeper in flight when the end-of-tile vmcnt(6) checks them.
__global__ __launch_bounds__(256, 2) void gemm_i8(
    const signed char* __restrict__ qxp, const signed char* __restrict__ qwp,
    const float* __restrict__ bias, const float* __restrict__ mulv,
    const unsigned* __restrict__ scales, float* __restrict__ out) {
    __shared__ signed char ldsA[3][8192];
    __shared__ signed char ldsB[3][16384];

    const int t    = threadIdx.x;   // 0..255
    const int lane = t & 63;
    const int ln   = lane & 31;
    const int hi   = lane >> 5;
    const int wc   = t >> 6;        // 0..3 (N quarter)

    // Supertile: xcd = orig&7 owns bm in [(xcd&1)*16,+16), bn in [(xcd>>1)*8,+8).
    // Bijective over 32x32 (bm,bn); per-XCD L2 working set = 4MB A + 4MB B.
    const int orig = blockIdx.x;
    const int xcd  = orig & 7;
    const int idx  = orig >> 3;               // 0..127
    const int bm   = (xcd & 1) * 16 + (idx >> 3);   // 0..31 (128-row panel)
    const int bn   = (xcd >> 1) * 8 + (idx & 7);    // 0..31 (256-col panel)

    const signed char* srcA = qxp + (size_t)bm * (32 * 8192);
    const signed char* srcB = qwp + (size_t)bn * (32 * 16384);
    signed char* dA0 = &ldsA[0][0] + t * 16;   // wave-uniform base + lane*16
    signed char* dB0 = &ldsB[0][0] + t * 16;

    auto stage = [&](int kt, int buf) {
        const signed char* sa = srcA + kt * 8192  + t * 16;
        const signed char* sb = srcB + kt * 16384 + t * 16;
        signed char* da = dA0 + buf * 8192;
        signed char* db = dB0 + buf * 16384;
        __builtin_amdgcn_global_load_lds((gas_ptr)sa,           (las_ptr)da,            16, 0, 0);
        __builtin_amdgcn_global_load_lds((gas_ptr)(sa + 4096),  (las_ptr)(da + 4096),   16, 0, 0);
        __builtin_amdgcn_global_load_lds((gas_ptr)sb,           (las_ptr)db,            16, 0, 0);
        __builtin_amdgcn_global_load_lds((gas_ptr)(sb + 4096),  (las_ptr)(db + 4096),   16, 0, 0);
        __builtin_amdgcn_global_load_lds((gas_ptr)(sb + 8192),  (las_ptr)(db + 8192),   16, 0, 0);
        __builtin_amdgcn_global_load_lds((gas_ptr)(sb + 12288), (las_ptr)(db + 12288),  16, 0, 0);
    };

    // fragment offsets: A plane stride 2048 (128 rows), B plane stride 4096.
    const int aOff = ln * 16;                  // + mt*512 + plane*2048
    const int bOff = (wc * 64 + ln) * 16;      // + nt*512 + plane*4096

    v16i acc[4][2];
#pragma unroll
    for (int mt = 0; mt < 4; ++mt)
#pragma unroll
        for (int nt = 0; nt < 2; ++nt)
#pragma unroll
            for (int r = 0; r < 16; ++r) acc[mt][nt][r] = 0;

    // ---- prologue: 2 tiles in flight; tile 0 resident before loop ----
    stage(0, 0);
    stage(1, 1);
    asm volatile("s_waitcnt vmcnt(6)" ::: "memory");   // tile 0 done
    __builtin_amdgcn_s_barrier();

    int cur = 0, stg = 2;
    for (int kt = 0; kt < NT; ++kt) {
        // stage first: global loads go deepest into the VMEM queue
        if (kt + 2 < NT) stage(kt + 2, stg);

        const signed char* Ab = &ldsA[cur][0];
        const signed char* Bb = &ldsB[cur][0];

        v4i a0[4], a1[4], b0[2], b1[2];
#pragma unroll
        for (int mt = 0; mt < 4; ++mt) a0[mt] = *(const v4i*)(Ab + hi * 2048 + aOff + mt * 512);
#pragma unroll
        for (int nt = 0; nt < 2; ++nt) b0[nt] = *(const v4i*)(Bb + hi * 4096 + bOff + nt * 512);
#pragma unroll
        for (int mt = 0; mt < 4; ++mt) a1[mt] = *(const v4i*)(Ab + (2 + hi) * 2048 + aOff + mt * 512);
#pragma unroll
        for (int nt = 0; nt < 2; ++nt) b1[nt] = *(const v4i*)(Bb + (2 + hi) * 4096 + bOff + nt * 512);

#pragma unroll
        for (int mt = 0; mt < 4; ++mt)
#pragma unroll
            for (int nt = 0; nt < 2; ++nt)
                acc[mt][nt] = __builtin_amdgcn_mfma_i32_32x32x32_i8(
                    a0[mt], b0[nt], acc[mt][nt], 0, 0, 0);
#pragma unroll
        for (int mt = 0; mt < 4; ++mt)
#pragma unroll
            for (int nt = 0; nt < 2; ++nt)
                acc[mt][nt] = __builtin_amdgcn_mfma_i32_32x32x32_i8(
                    a1[mt], b1[nt], acc[mt][nt], 0, 0, 0);

        // single end-of-tile sync: own staging retired, then block-wide barrier
        if (kt < NT - 1) {
            if (kt + 2 < NT) asm volatile("s_waitcnt vmcnt(6)" ::: "memory");
            else             asm volatile("s_waitcnt vmcnt(0)" ::: "memory");
            __builtin_amdgcn_s_barrier();
        }
        cur = (cur == 2) ? 0 : cur + 1;
        stg = (stg == 2) ? 0 : stg + 1;
    }

    // ---- epilogue: out = fs*acc + mul*bias (nontemporal C-stream) ----
    // C/D layout (32x32): col = lane&31, row = (r&3) + 8*(r>>2) + 4*(lane>>5)
    const float fm = mulv[0];
    const float fs = fm * (__uint_as_float(scales[0]) / 128.0f)
                        * (__uint_as_float(scales[1]) / 127.0f);
    const int colb = bn * 256 + wc * 64 + ln;
    const int hi4  = hi * 4;
#pragma unroll
    for (int nt = 0; nt < 2; ++nt) {
        const int ocol = colb + nt * 32;
        const float bv = bias[ocol] * fm;
#pragma unroll
        for (int mt = 0; mt < 4; ++mt) {
            float* op = out + (size_t)(bm * 128 + mt * 32) * NDIM + ocol;
#pragma unroll
            for (int r = 0; r < 16; ++r) {
                const int row = (r & 3) + 8 * (r >> 2) + hi4;
                __builtin_nontemporal_store(fs * (float)acc[mt][nt][r] + bv,
                                            op + (size_t)row * NDIM);
            }
        }
    }
}

extern "C" void kernel_launch(void* const* d_in, const int* in_sizes, int n_in,
                              void* d_out, int out_size, void* d_ws, size_t ws_size,
                              hipStream_t stream) {
    const float4* x    = (const float4*)d_in[0];
    const float4* wgt  = (const float4*)d_in[1];
    const float*  bias = (const float*)d_in[2];
    const float*  mulv = (const float*)d_in[3];
    float* out = (float*)d_out;

    // workspace: scales @0 (8B), partials @256 (12KB), qxp @16640, qwp next
    unsigned* scales  = (unsigned*)d_ws;
    float*    partial = (float*)((char*)d_ws + 256);
    signed char* qxp  = (signed char*)d_ws + 256 + 16384;
    signed char* qwp  = qxp + (size_t)MDIM * KDIM;

    absmax2<<<3072, 256, 0, stream>>>(x, wgt, partial);
    quant2<<<3072, 256, 0, stream>>>(x, (v4i*)qxp, wgt, (v4i*)qwp,
                                     partial, scales);
    gemm_i8<<<1024, 256, 0, stream>>>(qxp, qwp, bias, mulv, scales, out);
}

// Round 18
// 118.087 us; speedup vs baseline: 1.1301x; 1.1301x over previous
//
#include <hip/hip_runtime.h>

// Int8 fake-quant linear (exact integer accumulation):
//   sx = max|x|/128; qx = clamp(rint(x/sx),-128,127)
//   sw = max|w|/127; qw = clamp(rint(w/sw),-127,127)
//   out = mul * (sx*sw*(qx @ qw^T) + bias)
//
// qx permuted in 128-row blocks:  v4i idx = ((blk*32+kt)*4 + c)*128 + r
// qw permuted in 256-row blocks:  v4i idx = ((blk*32+kt)*4 + c)*256 + r
// Staging is a linear contiguous copy (global_load_lds); fragment reads are
// 32-lane contiguous (0 bank conflicts, verified R3/R5/R7/R12/R15).

typedef int v4i  __attribute__((ext_vector_type(4)));
typedef int v16i __attribute__((ext_vector_type(16)));

#define MDIM 4096
#define NDIM 8192
#define KDIM 2048
#define NT   (KDIM / 64)   // 32 K-tiles of BK=64 int8

typedef __attribute__((address_space(1))) void* gas_ptr;   // global
typedef __attribute__((address_space(3))) void* las_ptr;   // LDS

#define XBLK 1024   // blocks for x; w gets 2048 (total 3072)

// ---------------- absmax: per-block partial maxima (plain stores) ----------------
__global__ __launch_bounds__(256) void absmax2(const float4* __restrict__ x,
                                               const float4* __restrict__ w,
                                               float* __restrict__ partial) {
    const int tid = threadIdx.x;
    const bool isx = blockIdx.x < XBLK;
    float m0 = 0.0f, m1 = 0.0f;
    if (isx) {
        const size_t base = (size_t)blockIdx.x * 256 + tid;       // stride 262144
#pragma unroll
        for (int j = 0; j < 8; j += 2) {
            float4 v0 = x[base + (size_t)j * 262144];
            float4 v1 = x[base + (size_t)(j + 1) * 262144];
            m0 = fmaxf(m0, fmaxf(fmaxf(fabsf(v0.x), fabsf(v0.y)),
                                 fmaxf(fabsf(v0.z), fabsf(v0.w))));
            m1 = fmaxf(m1, fmaxf(fmaxf(fabsf(v1.x), fabsf(v1.y)),
                                 fmaxf(fabsf(v1.z), fabsf(v1.w))));
        }
    } else {
        const size_t base = (size_t)(blockIdx.x - XBLK) * 256 + tid;  // stride 524288
#pragma unroll
        for (int j = 0; j < 8; j += 2) {
            float4 v0 = w[base + (size_t)j * 524288];
            float4 v1 = w[base + (size_t)(j + 1) * 524288];
            m0 = fmaxf(m0, fmaxf(fmaxf(fabsf(v0.x), fabsf(v0.y)),
                                 fmaxf(fabsf(v0.z), fabsf(v0.w))));
            m1 = fmaxf(m1, fmaxf(fmaxf(fabsf(v1.x), fabsf(v1.y)),
                                 fmaxf(fabsf(v1.z), fabsf(v1.w))));
        }
    }
    float m = fmaxf(m0, m1);
#pragma unroll
    for (int off = 32; off > 0; off >>= 1)
        m = fmaxf(m, __shfl_xor(m, off, 64));
    __shared__ float wm[4];
    if ((tid & 63) == 0) wm[tid >> 6] = m;
    __syncthreads();
    if (tid == 0)
        partial[blockIdx.x] = fmaxf(fmaxf(wm[0], wm[1]), fmaxf(wm[2], wm[3]));
}

// ---------------- quantize: reduce partials, then permuted int8 write ----------
// x -> 128-row blocks; w -> 256-row blocks.
__global__ __launch_bounds__(256) void quant2(const float4* __restrict__ x,
                                              v4i* __restrict__ qxp,
                                              const float4* __restrict__ w,
                                              v4i* __restrict__ qwp,
                                              const float* __restrict__ partial,
                                              unsigned* __restrict__ scales) {
    const int tid = threadIdx.x;
    float gx = 0.0f, gw = 0.0f;
#pragma unroll
    for (int j = 0; j < 4; ++j) gx = fmaxf(gx, partial[tid + j * 256]);
#pragma unroll
    for (int j = 0; j < 8; ++j) gw = fmaxf(gw, partial[XBLK + tid + j * 256]);
#pragma unroll
    for (int off = 32; off > 0; off >>= 1) {
        gx = fmaxf(gx, __shfl_xor(gx, off, 64));
        gw = fmaxf(gw, __shfl_xor(gw, off, 64));
    }
    __shared__ float smx[4], smw[4];
    if ((tid & 63) == 0) { smx[tid >> 6] = gx; smw[tid >> 6] = gw; }
    __syncthreads();
    const float fmx = fmaxf(fmaxf(smx[0], smx[1]), fmaxf(smx[2], smx[3]));
    const float fmw = fmaxf(fmaxf(smw[0], smw[1]), fmaxf(smw[2], smw[3]));
    if (blockIdx.x == 0 && tid == 0) {
        scales[0] = __float_as_uint(fmx);
        scales[1] = __float_as_uint(fmw);
    }
    const float sxs = fmx / 128.0f;   // IEEE, matches reference scale
    const float sws = fmw / 127.0f;

    const bool isx = blockIdx.x < XBLK;
    const float4* in = isx ? x : w;
    v4i* outp = isx ? qxp : qwp;
    const int total = isx ? (MDIM * KDIM / 16) : (NDIM * KDIM / 16);
    const int nb = isx ? XBLK : (3072 - XBLK);
    const int b  = isx ? blockIdx.x : (blockIdx.x - XBLK);
    const float s  = isx ? sxs : sws;
    const float lo = isx ? -128.0f : -127.0f;
    for (int idx = b * 256 + tid; idx < total; idx += nb * 256) {
        int c, r, kt, blk, row, oidx;
        if (isx) {   // 128-row blocks
            c   = idx & 3;
            r   = (idx >> 2) & 127;
            kt  = (idx >> 9) & 31;
            blk = idx >> 14;
            row = blk * 128 + r;
            oidx = ((blk * 32 + kt) * 4 + c) * 128 + r;
        } else {     // 256-row blocks
            c   = idx & 3;
            r   = (idx >> 2) & 255;
            kt  = (idx >> 10) & 31;
            blk = idx >> 15;
            row = blk * 256 + r;
            oidx = ((blk * 32 + kt) * 4 + c) * 256 + r;
        }
        const float4* src = in + (size_t)row * (KDIM / 4) + kt * 16 + c * 4;
        int q[4];
#pragma unroll
        for (int j = 0; j < 4; ++j) {
            float4 v = src[j];
            int b0 = (int)fminf(fmaxf(rintf(v.x / s), lo), 127.0f);
            int b1 = (int)fminf(fmaxf(rintf(v.y / s), lo), 127.0f);
            int b2 = (int)fminf(fmaxf(rintf(v.z / s), lo), 127.0f);
            int b3 = (int)fminf(fmaxf(rintf(v.w / s), lo), 127.0f);
            q[j] = (b0 & 255) | ((b1 & 255) << 8) | ((b2 & 255) << 16) | (b3 << 24);
        }
        v4i qq; qq[0] = q[0]; qq[1] = q[1]; qq[2] = q[2]; qq[3] = q[3];
        outp[oidx] = qq;
    }
}

// ------- int8 MFMA GEMM: 128x256 tile, ring-3, 2 blocks/CU, 1 barrier/tile ---
// 256 threads = 4 waves (1M x 4N); wave output 128x64 = 4x2 mfma_i32_32x32x32.
// LDS: A 8KB + B 16KB per buffer, ring-3 = 72 KiB -> TWO blocks/CU (m114
// cross-block overlap, R15-proven). Supertile: each XCD owns 16 bm x 8 bn.
// SINGLE barrier per tile (R16-proven best): {12 ds_read_b128(t);
// stage kt+2 (6 loads); setprio(1) 16 MFMA setprio(0); vmcnt(6|0); s_barrier}.
// R17 A/B showed BOTH deviations regress: setprio removal (-~15%) and
// stage-before-reads (delays ds_read issue). Keep exactly this shape.
// Hazards: (RAW) own vmcnt(6) before bar retires tile t+1's staging in every
// wave -> visible to all after bar. (WAR) crossing the bar implies the wave's
// MFMAs issued, which forces its tile-t ds_reads complete (lgkm) -> next
// iter's stage(t+3) may overwrite buf t%3.
__global__ __launch_bounds__(256, 2) void gemm_i8(
    const signed char* __restrict__ qxp, const signed char* __restrict__ qwp,
    const float* __restrict__ bias, const float* __restrict__ mulv,
    const unsigned* __restrict__ scales, float* __restrict__ out) {
    __shared__ signed char ldsA[3][8192];
    __shared__ signed char ldsB[3][16384];

    const int t    = threadIdx.x;   // 0..255
    const int lane = t & 63;
    const int ln   = lane & 31;
    const int hi   = lane >> 5;
    const int wc   = t >> 6;        // 0..3 (N quarter)

    // Supertile: xcd = orig&7 owns bm in [(xcd&1)*16,+16), bn in [(xcd>>1)*8,+8).
    // Bijective over 32x32 (bm,bn); per-XCD L2 working set = 4MB A + 4MB B.
    const int orig = blockIdx.x;
    const int xcd  = orig & 7;
    const int idx  = orig >> 3;               // 0..127
    const int bm   = (xcd & 1) * 16 + (idx >> 3);   // 0..31 (128-row panel)
    const int bn   = (xcd >> 1) * 8 + (idx & 7);    // 0..31 (256-col panel)

    const signed char* srcA = qxp + (size_t)bm * (32 * 8192);
    const signed char* srcB = qwp + (size_t)bn * (32 * 16384);
    signed char* dA0 = &ldsA[0][0] + t * 16;   // wave-uniform base + lane*16
    signed char* dB0 = &ldsB[0][0] + t * 16;

    auto stage = [&](int kt, int buf) {
        const signed char* sa = srcA + kt * 8192  + t * 16;
        const signed char* sb = srcB + kt * 16384 + t * 16;
        signed char* da = dA0 + buf * 8192;
        signed char* db = dB0 + buf * 16384;
        __builtin_amdgcn_global_load_lds((gas_ptr)sa,           (las_ptr)da,            16, 0, 0);
        __builtin_amdgcn_global_load_lds((gas_ptr)(sa + 4096),  (las_ptr)(da + 4096),   16, 0, 0);
        __builtin_amdgcn_global_load_lds((gas_ptr)sb,           (las_ptr)db,            16, 0, 0);
        __builtin_amdgcn_global_load_lds((gas_ptr)(sb + 4096),  (las_ptr)(db + 4096),   16, 0, 0);
        __builtin_amdgcn_global_load_lds((gas_ptr)(sb + 8192),  (las_ptr)(db + 8192),   16, 0, 0);
        __builtin_amdgcn_global_load_lds((gas_ptr)(sb + 12288), (las_ptr)(db + 12288),  16, 0, 0);
    };

    // fragment offsets: A plane stride 2048 (128 rows), B plane stride 4096.
    const int aOff = ln * 16;                  // + mt*512 + plane*2048
    const int bOff = (wc * 64 + ln) * 16;      // + nt*512 + plane*4096

    v16i acc[4][2];
#pragma unroll
    for (int mt = 0; mt < 4; ++mt)
#pragma unroll
        for (int nt = 0; nt < 2; ++nt)
#pragma unroll
            for (int r = 0; r < 16; ++r) acc[mt][nt][r] = 0;

    // ---- prologue: 2 tiles in flight; tile 0 resident before loop ----
    stage(0, 0);
    stage(1, 1);
    asm volatile("s_waitcnt vmcnt(6)" ::: "memory");   // tile 0 done
    __builtin_amdgcn_s_barrier();

    int cur = 0, stg = 2;
    for (int kt = 0; kt < NT; ++kt) {
        const signed char* Ab = &ldsA[cur][0];
        const signed char* Bb = &ldsB[cur][0];

        v4i a0[4], a1[4], b0[2], b1[2];
#pragma unroll
        for (int mt = 0; mt < 4; ++mt) a0[mt] = *(const v4i*)(Ab + hi * 2048 + aOff + mt * 512);
#pragma unroll
        for (int nt = 0; nt < 2; ++nt) b0[nt] = *(const v4i*)(Bb + hi * 4096 + bOff + nt * 512);
#pragma unroll
        for (int mt = 0; mt < 4; ++mt) a1[mt] = *(const v4i*)(Ab + (2 + hi) * 2048 + aOff + mt * 512);
#pragma unroll
        for (int nt = 0; nt < 2; ++nt) b1[nt] = *(const v4i*)(Bb + (2 + hi) * 4096 + bOff + nt * 512);

        if (kt + 2 < NT) stage(kt + 2, stg);

        __builtin_amdgcn_s_setprio(1);
#pragma unroll
        for (int mt = 0; mt < 4; ++mt)
#pragma unroll
            for (int nt = 0; nt < 2; ++nt)
                acc[mt][nt] = __builtin_amdgcn_mfma_i32_32x32x32_i8(
                    a0[mt], b0[nt], acc[mt][nt], 0, 0, 0);
#pragma unroll
        for (int mt = 0; mt < 4; ++mt)
#pragma unroll
            for (int nt = 0; nt < 2; ++nt)
                acc[mt][nt] = __builtin_amdgcn_mfma_i32_32x32x32_i8(
                    a1[mt], b1[nt], acc[mt][nt], 0, 0, 0);
        __builtin_amdgcn_s_setprio(0);

        // single end-of-tile sync: own staging retired, then block-wide barrier
        if (kt < NT - 1) {
            if (kt + 2 < NT) asm volatile("s_waitcnt vmcnt(6)" ::: "memory");
            else             asm volatile("s_waitcnt vmcnt(0)" ::: "memory");
            __builtin_amdgcn_s_barrier();
        }
        cur = (cur == 2) ? 0 : cur + 1;
        stg = (stg == 2) ? 0 : stg + 1;
    }

    // ---- epilogue: out = fs*acc + mul*bias (nontemporal C-stream) ----
    // C/D layout (32x32): col = lane&31, row = (r&3) + 8*(r>>2) + 4*(lane>>5)
    const float fm = mulv[0];
    const float fs = fm * (__uint_as_float(scales[0]) / 128.0f)
                        * (__uint_as_float(scales[1]) / 127.0f);
    const int colb = bn * 256 + wc * 64 + ln;
    const int hi4  = hi * 4;
#pragma unroll
    for (int nt = 0; nt < 2; ++nt) {
        const int ocol = colb + nt * 32;
        const float bv = bias[ocol] * fm;
#pragma unroll
        for (int mt = 0; mt < 4; ++mt) {
            float* op = out + (size_t)(bm * 128 + mt * 32) * NDIM + ocol;
#pragma unroll
            for (int r = 0; r < 16; ++r) {
                const int row = (r & 3) + 8 * (r >> 2) + hi4;
                __builtin_nontemporal_store(fs * (float)acc[mt][nt][r] + bv,
                                            op + (size_t)row * NDIM);
            }
        }
    }
}

extern "C" void kernel_launch(void* const* d_in, const int* in_sizes, int n_in,
                              void* d_out, int out_size, void* d_ws, size_t ws_size,
                              hipStream_t stream) {
    const float4* x    = (const float4*)d_in[0];
    const float4* wgt  = (const float4*)d_in[1];
    const float*  bias = (const float*)d_in[2];
    const float*  mulv = (const float*)d_in[3];
    float* out = (float*)d_out;

    // workspace: scales @0 (8B), partials @256 (12KB), qxp @16640, qwp next
    unsigned* scales  = (unsigned*)d_ws;
    float*    partial = (float*)((char*)d_ws + 256);
    signed char* qxp  = (signed char*)d_ws + 256 + 16384;
    signed char* qwp  = qxp + (size_t)MDIM * KDIM;

    absmax2<<<3072, 256, 0, stream>>>(x, wgt, partial);
    quant2<<<3072, 256, 0, stream>>>(x, (v4i*)qxp, wgt, (v4i*)qwp,
                                     partial, scales);
    gemm_i8<<<1024, 256, 0, stream>>>(qxp, qwp, bias, mulv, scales, out);
}